// Round 8
// baseline (177.729 us; speedup 1.0000x reference)
//
#include <hip/hip_runtime.h>

typedef _Float16 v8h __attribute__((ext_vector_type(8)));
typedef float    v4f __attribute__((ext_vector_type(4)));

#define MFMA16(a, b, c) __builtin_amdgcn_mfma_f32_16x16x32_f16((a), (b), (c), 0, 0, 0)

#define GLL16(gptr, lptr)                                                        \
  __builtin_amdgcn_global_load_lds((const __attribute__((address_space(1))) void*)(gptr), \
                                   (__attribute__((address_space(3))) void*)(lptr), 16, 0, 0)

// Weight-fragment table in d_ws: 154 fragments, layout [frag][lane] of 8 x f16 (16B).
// Non-zero 32(k) x 16(n) tiles of the 480x480 block-diagonal Wbig:
//   ot 0..7   (cols   0..127): kt 0..3   fbase = ot*4
//   ot 8..19  (cols 128..319): kt 4..9   fbase = 32 + (ot-8)*6
//   ot 20..29 (cols 320..479): kt 10..14 fbase = 104 + (ot-20)*5
// Fragment convention (A and B slots identical): lane l, elem e holds
// k = kt*32 + (l>>4)*8 + e; other dim = l&15.
// SWAPPED use: W-frag in A slot, x-frag in B slot -> lane l, reg j =
// out[row l&15][col ot*16 + (l>>4)*4 + j] -> one float4 store per ot per slab.

__global__ void build_frags_k(const float* __restrict__ W0, const float* __restrict__ W1,
                              const float* __restrict__ W2, v8h* __restrict__ frag) {
  const int f = blockIdx.x;
  const int lane = threadIdx.x;
  int ot, kt;
  if (f < 32)       { ot = f >> 2;           kt = f & 3; }
  else if (f < 104) { int q = f - 32;  ot = 8 + q / 6;  kt = 4 + q % 6; }
  else              { int q = f - 104; ot = 20 + q / 5; kt = 10 + q % 5; }
  const int n  = ot * 16 + (lane & 15);
  const int kb = kt * 32 + (lane >> 4) * 8;
  v8h v;
#pragma unroll
  for (int e = 0; e < 8; ++e) {
    const int k = kb + e;
    float wv = 0.0f;
    if (k < 128) {
      if (n < 128) wv = W0[k * 128 + n] * 0.08838834764831845f;           // 1/sqrt(128)
    } else if (k < 320) {
      if (n >= 128 && n < 320) {
        const int i = k - 128, o = n - 128;
        if (i % 3 == o % 3) wv = W1[(i / 3) * 64 + (o / 3)] * 0.125f;     // 1/sqrt(64)
      }
    } else {
      if (n >= 320) {
        const int i = k - 320, o = n - 320;
        if (i % 5 == o % 5) wv = W2[(i / 5) * 32 + (o / 5)] * 0.17677669529663687f; // 1/sqrt(32)
      }
    }
    v[e] = (_Float16)wv;
  }
  frag[f * 64 + lane] = v;
}

// Persistent 512-thread blocks, 1/CU. Wave w owns ots {w, 8+w, 16+w[, 24+w]}:
//   V=0 (w 0..3): cb[0,1,1,2], 21 frags;  V=1 (w 4,5): cb[0,1,2,2], 20 frags;
//   V=2 (w 6,7): cb[0,1,2], 15 frags.  B-frags live in registers for the whole
// kernel -> frag L2 traffic 962MB -> 39MB. Tiles of 32 rows double-buffered in
// LDS (2x61440B) via global_load_lds with source-side bank swizzle; counted
// s_waitcnt vmcnt(N) keeps ONLY the next tile's loads in flight across the
// barrier (never drains the prefetch).
template <int V>
__device__ __forceinline__ void wave_main(const float* __restrict__ x,
                                          const v8h* __restrict__ frag,
                                          float* __restrict__ out,
                                          unsigned char* sm, int t, int t0, int t1) {
  const int lane = t & 63;
  const int w    = t >> 6;
  const int r16  = lane & 15;
  const int g    = lane >> 4;

  // ---- persistent B-fragments (compile-time register indices) ----
  constexpr int NF = (V == 0) ? 21 : (V == 1) ? 20 : 15;
  v8h f[NF];
  {
    const int fb0 = w * 4;
    const int fb1 = 32 + w * 6;
#pragma unroll
    for (int k = 0; k < 4; ++k) f[k] = frag[(fb0 + k) * 64 + lane];
#pragma unroll
    for (int k = 0; k < 6; ++k) f[4 + k] = frag[(fb1 + k) * 64 + lane];
    if constexpr (V == 0) {
      const int fb2 = 32 + (8 + w) * 6;       // ot 16+w (cb1)
      const int fb3 = 104 + (4 + w) * 5;      // ot 24+w (cb2)
#pragma unroll
      for (int k = 0; k < 6; ++k) f[10 + k] = frag[(fb2 + k) * 64 + lane];
#pragma unroll
      for (int k = 0; k < 5; ++k) f[16 + k] = frag[(fb3 + k) * 64 + lane];
    } else if constexpr (V == 1) {
      const int fb2 = 104 + (w - 4) * 5;      // ot 16+w (cb2)
      const int fb3 = 104 + (w + 4) * 5;      // ot 24+w (cb2)
#pragma unroll
      for (int k = 0; k < 5; ++k) f[10 + k] = frag[(fb2 + k) * 64 + lane];
#pragma unroll
      for (int k = 0; k < 5; ++k) f[15 + k] = frag[(fb3 + k) * 64 + lane];
    } else {
      const int fb2 = 104 + (w - 4) * 5;      // ot 16+w (cb2)
#pragma unroll
      for (int k = 0; k < 5; ++k) f[10 + k] = frag[(fb2 + k) * 64 + lane];
    }
  }

  // ---- staging: 32 rows x 1920B = 3840 granules; 7.5 gll/thread ----
  auto stage = [&](int tt, int bsel) {
    const unsigned char* xt = (const unsigned char*)x + (size_t)tt * 61440u;
    unsigned char* buf = sm + bsel * 61440;
#pragma unroll
    for (int i = 0; i < 8; ++i) {
      if (i < 7 || t < 256) {                  // wave-uniform (waves 0..3 do i=7)
        const unsigned gl = (unsigned)(i * 512 + t);
        const unsigned r  = gl / 120u;
        const unsigned j  = gl - r * 120u;
        GLL16(xt + r * 1920u + ((j ^ (r & 7u)) << 4), buf + i * 8192 + w * 1024);
      }
    }
  };

#define LDAF(kt, dst)                                                                       \
  {                                                                                         \
    const unsigned j0 = (unsigned)((kt) * 8 + g * 2);                                       \
    const float4 lo = *reinterpret_cast<const float4*>(smc + rb + (((j0) ^ q) << 4));       \
    const float4 hi = *reinterpret_cast<const float4*>(smc + rb + ((((j0) + 1) ^ q) << 4)); \
    v8h v_;                                                                                 \
    v_[0] = (_Float16)lo.x; v_[1] = (_Float16)lo.y;                                         \
    v_[2] = (_Float16)lo.z; v_[3] = (_Float16)lo.w;                                         \
    v_[4] = (_Float16)hi.x; v_[5] = (_Float16)hi.y;                                         \
    v_[6] = (_Float16)hi.z; v_[7] = (_Float16)hi.w;                                         \
    dst = v_;                                                                               \
  }

  auto compute = [&](int tt, int bsel) {
    const unsigned char* smc = sm + bsel * 61440;
#pragma unroll
    for (int sl = 0; sl < 2; ++sl) {
      const unsigned row = (unsigned)(sl * 16 + r16);
      const unsigned rb  = row * 1920u;
      const unsigned q   = row & 7u;
      float* const ob = out + ((size_t)tt * 32 + sl * 16 + r16) * 480 + g * 4;
      {  // cb0: kts 0..3, ot = w
        v8h x0[4];
#pragma unroll
        for (int k = 0; k < 4; ++k) LDAF(k, x0[k]);
        v4f a0 = {0.f, 0.f, 0.f, 0.f};
#pragma unroll
        for (int k = 0; k < 4; ++k) a0 = MFMA16(f[k], x0[k], a0);
        *reinterpret_cast<v4f*>(ob + w * 16) = a0;
      }
      {  // cb1: kts 4..9, ots 8+w (and 16+w for V=0)
        v8h x1[6];
#pragma unroll
        for (int k = 0; k < 6; ++k) LDAF(4 + k, x1[k]);
        v4f a1 = {0.f, 0.f, 0.f, 0.f};
#pragma unroll
        for (int k = 0; k < 6; ++k) a1 = MFMA16(f[4 + k], x1[k], a1);
        *reinterpret_cast<v4f*>(ob + (8 + w) * 16) = a1;
        if constexpr (V == 0) {
          v4f a2 = {0.f, 0.f, 0.f, 0.f};
#pragma unroll
          for (int k = 0; k < 6; ++k) a2 = MFMA16(f[10 + k], x1[k], a2);
          *reinterpret_cast<v4f*>(ob + (16 + w) * 16) = a2;
        }
      }
      {  // cb2: kts 10..14
        v8h x2[5];
#pragma unroll
        for (int k = 0; k < 5; ++k) LDAF(10 + k, x2[k]);
        if constexpr (V == 0) {
          v4f a3 = {0.f, 0.f, 0.f, 0.f};
#pragma unroll
          for (int k = 0; k < 5; ++k) a3 = MFMA16(f[16 + k], x2[k], a3);
          *reinterpret_cast<v4f*>(ob + (24 + w) * 16) = a3;
        } else if constexpr (V == 1) {
          v4f a2 = {0.f, 0.f, 0.f, 0.f}, a3 = {0.f, 0.f, 0.f, 0.f};
#pragma unroll
          for (int k = 0; k < 5; ++k) {
            a2 = MFMA16(f[10 + k], x2[k], a2);
            a3 = MFMA16(f[15 + k], x2[k], a3);
          }
          *reinterpret_cast<v4f*>(ob + (16 + w) * 16) = a2;
          *reinterpret_cast<v4f*>(ob + (24 + w) * 16) = a3;
        } else {
          v4f a2 = {0.f, 0.f, 0.f, 0.f};
#pragma unroll
          for (int k = 0; k < 5; ++k) a2 = MFMA16(f[10 + k], x2[k], a2);
          *reinterpret_cast<v4f*>(ob + (16 + w) * 16) = a2;
        }
      }
    }
  };

  // ---- pipelined tile loop ----
  // vmcnt(N): N = this wave's gll count per tile (V0: 8, V1/V2: 7). At each
  // wait, ops younger than gll(t) are stores(t-1) + gll(t+1) >= N, and gll(t)
  // is oldest -> "<= N outstanding" proves gll(t) (and prior stores) retired,
  // while gll(t+1) stays in flight across the barrier.
  stage(t0, 0);
  int tt = t0;
  for (; tt < t1 - 1; ++tt) {
    const int cur = (tt - t0) & 1;
    stage(tt + 1, cur ^ 1);
    if constexpr (V == 0) asm volatile("s_waitcnt vmcnt(8)" ::: "memory");
    else                  asm volatile("s_waitcnt vmcnt(7)" ::: "memory");
    __builtin_amdgcn_s_barrier();
    compute(tt, cur);
    __builtin_amdgcn_s_barrier();
  }
  {  // final tile: no prefetch, full drain
    const int cur = (tt - t0) & 1;
    asm volatile("s_waitcnt vmcnt(0)" ::: "memory");
    __builtin_amdgcn_s_barrier();
    compute(tt, cur);
  }
#undef LDAF
}

__global__ __launch_bounds__(512, 2) void irrep_linear_k(
    const float* __restrict__ x, const v8h* __restrict__ frag, float* __restrict__ out,
    int base_tpb, int rem) {
  __shared__ __align__(16) unsigned char sm[2 * 61440];
  const int t = threadIdx.x;
  const int b = blockIdx.x;
  const int t0 = b * base_tpb + (b < rem ? b : rem);
  const int t1 = t0 + base_tpb + (b < rem ? 1 : 0);
  const int w = t >> 6;
  if (w < 4)      wave_main<0>(x, frag, out, sm, t, t0, t1);
  else if (w < 6) wave_main<1>(x, frag, out, sm, t, t0, t1);
  else            wave_main<2>(x, frag, out, sm, t, t0, t1);
}

extern "C" void kernel_launch(void* const* d_in, const int* in_sizes, int n_in,
                              void* d_out, int out_size, void* d_ws, size_t ws_size,
                              hipStream_t stream) {
  const float* x  = (const float*)d_in[0];
  const float* W0 = (const float*)d_in[1];
  const float* W1 = (const float*)d_in[2];
  const float* W2 = (const float*)d_in[3];
  float* out = (float*)d_out;
  v8h* frag = (v8h*)d_ws;   // 154 * 64 * 16 B = 157,696 B

  build_frags_k<<<154, 64, 0, stream>>>(W0, W1, W2, frag);

  const int N = in_sizes[0] / 480;        // 200000
  const int n_tiles = N / 32;             // 6250 tiles of 32 rows
  const int nblk = 256;                   // persistent, 1 block/CU
  const int base_tpb = n_tiles / nblk;    // 24
  const int rem = n_tiles - base_tpb * nblk;  // 106
  irrep_linear_k<<<nblk, 512, 0, stream>>>(x, frag, out, base_tpb, rem);
}

// Round 9
// 175.064 us; speedup vs baseline: 1.0152x; 1.0152x over previous
//
#include <hip/hip_runtime.h>

typedef _Float16 v8h __attribute__((ext_vector_type(8)));
typedef float    v4f __attribute__((ext_vector_type(4)));

#define MFMA16(a, b, c) __builtin_amdgcn_mfma_f32_16x16x32_f16((a), (b), (c), 0, 0, 0)

#define GLL16(gptr, lptr)                                                        \
  __builtin_amdgcn_global_load_lds((const __attribute__((address_space(1))) void*)(gptr), \
                                   (__attribute__((address_space(3))) void*)(lptr), 16, 0, 0)

// Weight-fragment table in d_ws: 154 fragments, layout [frag][lane] of 8 x f16 (16B).
// Non-zero 32(k) x 16(n) tiles of the 480x480 block-diagonal Wbig:
//   ot 0..7   (cols   0..127): kt 0..3   fbase = ot*4
//   ot 8..19  (cols 128..319): kt 4..9   fbase = 32 + (ot-8)*6
//   ot 20..29 (cols 320..479): kt 10..14 fbase = 104 + (ot-20)*5
// Fragment convention (A and B slots identical): lane l, elem e holds
// k = kt*32 + (l>>4)*8 + e; other dim = l&15.
// SWAPPED use: W-frag in A slot, x-frag in B slot -> lane l, reg j =
// out[row l&15][col ot*16 + (l>>4)*4 + j] -> one float4 store per ot per slab.

__global__ void build_frags_k(const float* __restrict__ W0, const float* __restrict__ W1,
                              const float* __restrict__ W2, v8h* __restrict__ frag) {
  const int f = blockIdx.x;
  const int lane = threadIdx.x;
  int ot, kt;
  if (f < 32)       { ot = f >> 2;           kt = f & 3; }
  else if (f < 104) { int q = f - 32;  ot = 8 + q / 6;  kt = 4 + q % 6; }
  else              { int q = f - 104; ot = 20 + q / 5; kt = 10 + q % 5; }
  const int n  = ot * 16 + (lane & 15);
  const int kb = kt * 32 + (lane >> 4) * 8;
  v8h v;
#pragma unroll
  for (int e = 0; e < 8; ++e) {
    const int k = kb + e;
    float wv = 0.0f;
    if (k < 128) {
      if (n < 128) wv = W0[k * 128 + n] * 0.08838834764831845f;           // 1/sqrt(128)
    } else if (k < 320) {
      if (n >= 128 && n < 320) {
        const int i = k - 128, o = n - 128;
        if (i % 3 == o % 3) wv = W1[(i / 3) * 64 + (o / 3)] * 0.125f;     // 1/sqrt(64)
      }
    } else {
      if (n >= 320) {
        const int i = k - 320, o = n - 320;
        if (i % 5 == o % 5) wv = W2[(i / 5) * 32 + (o / 5)] * 0.17677669529663687f; // 1/sqrt(32)
      }
    }
    v[e] = (_Float16)wv;
  }
  frag[f * 64 + lane] = v;
}

// Persistent 512-thread blocks, 1/CU. Wave w owns ots {w, 8+w, 16+w[, 24+w]};
// B-frags register-resident for the whole kernel. Tiles of 32 rows double-
// buffered in LDS via global_load_lds (source-side bank swizzle).
//
// vmcnt discipline (in-order retirement; G = gll/tile, S = stores/tile):
//   per-iteration op order is  gll(t) [G] ... stores(t-1) [S] ... gll(t+1) [G].
//   Steady wait = vmcnt(G+S): retires exactly gll(t); stores(t-1) AND
//   gll(t+1) stay in flight -> store drain never gates compute (the round-8
//   limiter: vmcnt(G) coupled each tile to the previous tile's write drain).
//   First iteration (no prior stores): vmcnt(G). Last tile: vmcnt(S).
template <int V>
__device__ __forceinline__ void wave_main(const float* __restrict__ x,
                                          const v8h* __restrict__ frag,
                                          float* __restrict__ out,
                                          unsigned char* sm, int t, int t0, int t1) {
  const int lane = t & 63;
  const int w    = t >> 6;
  const int r16  = lane & 15;
  const int g    = lane >> 4;

  constexpr int G = (V == 0) ? 8 : 7;            // gll per wave per tile
  constexpr int S = (V == 2) ? 6 : 8;            // stores per wave per tile

  // ---- persistent B-fragments (compile-time register indices) ----
  constexpr int NF = (V == 0) ? 21 : (V == 1) ? 20 : 15;
  v8h f[NF];
  {
    const int fb0 = w * 4;
    const int fb1 = 32 + w * 6;
#pragma unroll
    for (int k = 0; k < 4; ++k) f[k] = frag[(fb0 + k) * 64 + lane];
#pragma unroll
    for (int k = 0; k < 6; ++k) f[4 + k] = frag[(fb1 + k) * 64 + lane];
    if constexpr (V == 0) {
      const int fb2 = 32 + (8 + w) * 6;       // ot 16+w (cb1)
      const int fb3 = 104 + (4 + w) * 5;      // ot 24+w (cb2)
#pragma unroll
      for (int k = 0; k < 6; ++k) f[10 + k] = frag[(fb2 + k) * 64 + lane];
#pragma unroll
      for (int k = 0; k < 5; ++k) f[16 + k] = frag[(fb3 + k) * 64 + lane];
    } else if constexpr (V == 1) {
      const int fb2 = 104 + (w - 4) * 5;      // ot 16+w (cb2)
      const int fb3 = 104 + (w + 4) * 5;      // ot 24+w (cb2)
#pragma unroll
      for (int k = 0; k < 5; ++k) f[10 + k] = frag[(fb2 + k) * 64 + lane];
#pragma unroll
      for (int k = 0; k < 5; ++k) f[15 + k] = frag[(fb3 + k) * 64 + lane];
    } else {
      const int fb2 = 104 + (w - 4) * 5;      // ot 16+w (cb2)
#pragma unroll
      for (int k = 0; k < 5; ++k) f[10 + k] = frag[(fb2 + k) * 64 + lane];
    }
  }

  // ---- staging: 32 rows x 1920B = 3840 granules; 7.5 gll/thread ----
  auto stage = [&](int tt, int bsel) {
    const unsigned char* xt = (const unsigned char*)x + (size_t)tt * 61440u;
    unsigned char* buf = sm + bsel * 61440;
#pragma unroll
    for (int i = 0; i < 8; ++i) {
      if (i < 7 || t < 256) {                  // wave-uniform (waves 0..3 do i=7)
        const unsigned gl = (unsigned)(i * 512 + t);
        const unsigned r  = gl / 120u;
        const unsigned j  = gl - r * 120u;
        GLL16(xt + r * 1920u + ((j ^ (r & 7u)) << 4), buf + i * 8192 + w * 1024);
      }
    }
  };

#define LDAF(kt, dst)                                                                       \
  {                                                                                         \
    const unsigned j0 = (unsigned)((kt) * 8 + g * 2);                                       \
    const float4 lo = *reinterpret_cast<const float4*>(smc + rb + (((j0) ^ q) << 4));       \
    const float4 hi = *reinterpret_cast<const float4*>(smc + rb + ((((j0) + 1) ^ q) << 4)); \
    v8h v_;                                                                                 \
    v_[0] = (_Float16)lo.x; v_[1] = (_Float16)lo.y;                                         \
    v_[2] = (_Float16)lo.z; v_[3] = (_Float16)lo.w;                                         \
    v_[4] = (_Float16)hi.x; v_[5] = (_Float16)hi.y;                                         \
    v_[6] = (_Float16)hi.z; v_[7] = (_Float16)hi.w;                                         \
    dst = v_;                                                                               \
  }

  auto compute = [&](int tt, int bsel) {
    const unsigned char* smc = sm + bsel * 61440;
#pragma unroll
    for (int sl = 0; sl < 2; ++sl) {
      const unsigned row = (unsigned)(sl * 16 + r16);
      const unsigned rb  = row * 1920u;
      const unsigned q   = row & 7u;
      float* const ob = out + ((size_t)tt * 32 + sl * 16 + r16) * 480 + g * 4;
      {  // cb0: kts 0..3, ot = w
        v8h x0[4];
#pragma unroll
        for (int k = 0; k < 4; ++k) LDAF(k, x0[k]);
        v4f a0 = {0.f, 0.f, 0.f, 0.f};
#pragma unroll
        for (int k = 0; k < 4; ++k) a0 = MFMA16(f[k], x0[k], a0);
        *reinterpret_cast<v4f*>(ob + w * 16) = a0;
      }
      {  // cb1: kts 4..9, ots 8+w (and 16+w for V=0)
        v8h x1[6];
#pragma unroll
        for (int k = 0; k < 6; ++k) LDAF(4 + k, x1[k]);
        v4f a1 = {0.f, 0.f, 0.f, 0.f};
#pragma unroll
        for (int k = 0; k < 6; ++k) a1 = MFMA16(f[4 + k], x1[k], a1);
        *reinterpret_cast<v4f*>(ob + (8 + w) * 16) = a1;
        if constexpr (V == 0) {
          v4f a2 = {0.f, 0.f, 0.f, 0.f};
#pragma unroll
          for (int k = 0; k < 6; ++k) a2 = MFMA16(f[10 + k], x1[k], a2);
          *reinterpret_cast<v4f*>(ob + (16 + w) * 16) = a2;
        }
      }
      {  // cb2: kts 10..14
        v8h x2[5];
#pragma unroll
        for (int k = 0; k < 5; ++k) LDAF(10 + k, x2[k]);
        if constexpr (V == 0) {
          v4f a3 = {0.f, 0.f, 0.f, 0.f};
#pragma unroll
          for (int k = 0; k < 5; ++k) a3 = MFMA16(f[16 + k], x2[k], a3);
          *reinterpret_cast<v4f*>(ob + (24 + w) * 16) = a3;
        } else if constexpr (V == 1) {
          v4f a2 = {0.f, 0.f, 0.f, 0.f}, a3 = {0.f, 0.f, 0.f, 0.f};
#pragma unroll
          for (int k = 0; k < 5; ++k) {
            a2 = MFMA16(f[10 + k], x2[k], a2);
            a3 = MFMA16(f[15 + k], x2[k], a3);
          }
          *reinterpret_cast<v4f*>(ob + (16 + w) * 16) = a2;
          *reinterpret_cast<v4f*>(ob + (24 + w) * 16) = a3;
        } else {
          v4f a2 = {0.f, 0.f, 0.f, 0.f};
#pragma unroll
          for (int k = 0; k < 5; ++k) a2 = MFMA16(f[10 + k], x2[k], a2);
          *reinterpret_cast<v4f*>(ob + (16 + w) * 16) = a2;
        }
      }
    }
  };

  // ---- pipelined tile loop (first/last peeled for store-decoupled waits) ----
  stage(t0, 0);
  stage(t0 + 1, 1);
  asm volatile("s_waitcnt vmcnt(%0)" :: "n"(G) : "memory");   // no prior stores
  __builtin_amdgcn_s_barrier();
  compute(t0, 0);
  __builtin_amdgcn_s_barrier();

  int tt = t0 + 1;
  for (; tt < t1 - 1; ++tt) {
    const int cur = (tt - t0) & 1;
    stage(tt + 1, cur ^ 1);
    asm volatile("s_waitcnt vmcnt(%0)" :: "n"(G + S) : "memory"); // gll(t) only
    __builtin_amdgcn_s_barrier();
    compute(tt, cur);
    __builtin_amdgcn_s_barrier();
  }
  {  // final tile: retire gll(t1-1), leave stores(t1-2) in flight
    const int cur = (tt - t0) & 1;
    asm volatile("s_waitcnt vmcnt(%0)" :: "n"(S) : "memory");
    __builtin_amdgcn_s_barrier();
    compute(tt, cur);
  }
#undef LDAF
}

__global__ __launch_bounds__(512, 2) void irrep_linear_k(
    const float* __restrict__ x, const v8h* __restrict__ frag, float* __restrict__ out,
    int base_tpb, int rem) {
  __shared__ __align__(16) unsigned char sm[2 * 61440];
  const int t = threadIdx.x;
  const int b = blockIdx.x;
  const int t0 = b * base_tpb + (b < rem ? b : rem);
  const int t1 = t0 + base_tpb + (b < rem ? 1 : 0);
  const int w = t >> 6;
  if (w < 4)      wave_main<0>(x, frag, out, sm, t, t0, t1);
  else if (w < 6) wave_main<1>(x, frag, out, sm, t, t0, t1);
  else            wave_main<2>(x, frag, out, sm, t, t0, t1);
}

extern "C" void kernel_launch(void* const* d_in, const int* in_sizes, int n_in,
                              void* d_out, int out_size, void* d_ws, size_t ws_size,
                              hipStream_t stream) {
  const float* x  = (const float*)d_in[0];
  const float* W0 = (const float*)d_in[1];
  const float* W1 = (const float*)d_in[2];
  const float* W2 = (const float*)d_in[3];
  float* out = (float*)d_out;
  v8h* frag = (v8h*)d_ws;   // 154 * 64 * 16 B = 157,696 B

  build_frags_k<<<154, 64, 0, stream>>>(W0, W1, W2, frag);

  const int N = in_sizes[0] / 480;        // 200000
  const int n_tiles = N / 32;             // 6250 tiles of 32 rows
  const int nblk = 256;                   // persistent, 1 block/CU
  const int base_tpb = n_tiles / nblk;    // 24
  const int rem = n_tiles - base_tpb * nblk;  // 106
  irrep_linear_k<<<nblk, 512, 0, stream>>>(x, frag, out, base_tpb, rem);
}